// Round 3
// baseline (1519.926 us; speedup 1.0000x reference)
//
#include <hip/hip_runtime.h>
#include <hip/hip_bf16.h>
#include <stdint.h>

#define NPTS 50000
#define NPAD 50048   // 391 * 128 row tiles

typedef unsigned short u16;
typedef __attribute__((ext_vector_type(8))) __bf16 bf16x8;
typedef __attribute__((ext_vector_type(4))) float f32x4;

__device__ __forceinline__ float bf2f(__hip_bfloat16 v) { return __bfloat162float(v); }
__device__ __forceinline__ __hip_bfloat16 f2bf(float v) { return __float2bfloat16(v); }
__device__ __forceinline__ int clampi(int v) { return v < 0 ? 0 : (v >= NPTS ? NPTS - 1 : v); }

// monotone float <-> uint encode for atomicMax over signed floats
__device__ __forceinline__ unsigned enc_f32(float f) {
    unsigned b = __float_as_uint(f);
    return (b & 0x80000000u) ? ~b : (b | 0x80000000u);
}
__device__ __forceinline__ float dec_f32(unsigned u) {
    return (u & 0x80000000u) ? __uint_as_float(u & 0x7fffffffu) : __uint_as_float(~u);
}

// async global->LDS, 16B per lane; LDS dest must be wave-uniform base + lane*16
__device__ __forceinline__ void gload_lds16(const void* g, void* l) {
    __builtin_amdgcn_global_load_lds((__attribute__((address_space(1))) void*)g,
                                     (__attribute__((address_space(3))) void*)l, 16, 0, 0);
}

// ---------------------------------------------------------------------------
// prep: zero-pad W_c1 (256x195)->fp32, W_a1 (256x131)->fp32+bf16; g_enc=-inf
// ---------------------------------------------------------------------------
__global__ __launch_bounds__(256) void prep(
    const float* __restrict__ W_c1, const float* __restrict__ W_a1,
    float* __restrict__ Wc1p, float* __restrict__ Wa1pf, __hip_bfloat16* __restrict__ Wa1pb,
    unsigned* __restrict__ g_enc)
{
    int i = blockIdx.x * 256 + threadIdx.x;
    if (i < 65536) {
        int o = i >> 8, k = i & 255;
        Wc1p[i] = (k < 195) ? W_c1[o * 195 + k] : 0.f;
    } else if (i < 131072) {
        int t = i - 65536;
        int o = t >> 8, k = t & 255;
        float v = (k < 131) ? W_a1[o * 131 + k] : 0.f;
        Wa1pf[t] = v;
        Wa1pb[t] = f2bf(v);
    } else if (i < 132096) {
        g_enc[i - 131072] = 0x007FFFFFu;   // enc(-inf)
    }
}

// ---------------------------------------------------------------------------
// wgemm (fp32): C[i][j] = sum_k A[i*lda+k]*B[k*ldb+j] (+ D[i*ldd+j]).
// M,N,K multiples of 32. 32x32 tiles. Writes fp32 (Cf) and/or bf16 (Cb).
// ---------------------------------------------------------------------------
__global__ __launch_bounds__(256) void wgemm(
    const float* __restrict__ A, int lda,
    const float* __restrict__ B, int ldb,
    const float* __restrict__ D, int ldd,
    float* __restrict__ Cf, __hip_bfloat16* __restrict__ Cb, int ldc,
    int K)
{
    __shared__ float sA[32][33], sB[32][33];
    const int bj = blockIdx.x, bi = blockIdx.y;
    const int t = threadIdx.x, tx = t & 31, ty = t >> 5;   // ty in [0,8)
    float acc[4] = {0.f, 0.f, 0.f, 0.f};
    for (int k0 = 0; k0 < K; k0 += 32) {
#pragma unroll
        for (int q = 0; q < 4; ++q) {
            int idx = q * 256 + t, r = idx >> 5, c = idx & 31;
            sA[r][c] = A[(long)(bi * 32 + r) * lda + k0 + c];
            sB[r][c] = B[(long)(k0 + r) * ldb + bj * 32 + c];
        }
        __syncthreads();
#pragma unroll 8
        for (int c = 0; c < 32; ++c) {
            float bv = sB[c][tx];
#pragma unroll
            for (int q = 0; q < 4; ++q) acc[q] += sA[ty + q * 8][c] * bv;
        }
        __syncthreads();
    }
#pragma unroll
    for (int q = 0; q < 4; ++q) {
        int r = bi * 32 + ty + q * 8, cidx = bj * 32 + tx;
        float v = acc[q];
        if (D)  v += D[(long)r * ldd + cidx];
        if (Cf) Cf[(long)r * ldc + cidx] = v;
        if (Cb) Cb[(long)r * ldc + cidx] = f2bf(v);
    }
}

// cvec[i] = b_f@M3^T + b_c2@T3^T + b_a2@T4^T + b_c1@U1^T + b_a1@U2^T
__global__ __launch_bounds__(256) void cvec_kernel(
    const float* __restrict__ W_m2,
    const float* __restrict__ T3f, const float* __restrict__ T4f,
    const float* __restrict__ U1f, const float* __restrict__ U2f,
    const float* __restrict__ b_f, const float* __restrict__ b_c2,
    const float* __restrict__ b_a2, const float* __restrict__ b_c1,
    const float* __restrict__ b_a1,
    float* __restrict__ cvec)
{
    int i = blockIdx.x * 256 + threadIdx.x;
    if (i >= 1024) return;
    float s = 0.f;
    for (int k = 0; k < 1024; ++k) s += b_f[k] * W_m2[(long)i * 1792 + 768 + k];
    for (int k = 0; k < 512;  ++k) s += b_c2[k] * T3f[i * 512 + k];
    for (int k = 0; k < 512;  ++k) s += b_a2[k] * T4f[i * 512 + k];
    for (int k = 0; k < 256;  ++k) s += b_c1[k] * U1f[i * 256 + k];
    for (int k = 0; k < 256;  ++k) s += b_a1[k] * U2f[i * 256 + k];
    cvec[i] = s;
}

// ---------------------------------------------------------------------------
// featurize: one wave per point. cat1 row (ld 256):
//   [0:64) spatial | [64:128) frc | [128:192) kc | [192:195) normal | zeros
// rows [NPTS,NPAD) zero-filled.
// ---------------------------------------------------------------------------
__global__ __launch_bounds__(256) void featurize(
    const float* __restrict__ centre, const float* __restrict__ corner,
    const float* __restrict__ normal, const int* __restrict__ neighbour,
    const float* __restrict__ W_sp2, const float* __restrict__ b_sp2,
    const float* __restrict__ W_sp1, const float* __restrict__ b_sp1,
    const float* __restrict__ conv_w, const float* __restrict__ conv_b,
    const float* __restrict__ W_fr3, const float* __restrict__ b_fr3,
    const float* __restrict__ W_fr4, const float* __restrict__ b_fr4,
    const float* __restrict__ theta, const float* __restrict__ phi,
    __hip_bfloat16* __restrict__ cat1)
{
    __shared__ float sWsp2t[3][64];  __shared__ float sbsp2[64];
    __shared__ float sWsp1t[64][64]; __shared__ float sbsp1[64];   // [k][j] transposed
    __shared__ float sconvt[6][32];  __shared__ float sconvb[32];
    __shared__ float sWfr3t[32][64]; __shared__ float sbfr3[64];
    __shared__ float sWfr4t[64][64]; __shared__ float sbfr4[64];
    __shared__ float ktx[256], kty[256], ktz[256];
    __shared__ float h1buf[4][64], mbuf[4][32], h3buf[4][64];

    const int tid = threadIdx.x;
    for (int i = tid; i < 4096; i += 256) { int j = i >> 6, k = i & 63; sWsp1t[k][j] = W_sp1[i]; }
    for (int i = tid; i < 4096; i += 256) { int j = i >> 6, k = i & 63; sWfr4t[k][j] = W_fr4[i]; }
    for (int i = tid; i < 2048; i += 256) { int j = i >> 5, k = i & 31; sWfr3t[k][j] = W_fr3[i]; }
    for (int i = tid; i < 192; i += 256) { int j = i / 3, k = i % 3; sWsp2t[k][j] = W_sp2[i]; }
    for (int i = tid; i < 192; i += 256) { int o = i / 6, k = i % 6; sconvt[k][o] = conv_w[i]; }
    if (tid < 64) {
        sbsp2[tid] = b_sp2[tid]; sbsp1[tid] = b_sp1[tid];
        sbfr3[tid] = b_fr3[tid]; sbfr4[tid] = b_fr4[tid];
    }
    if (tid < 32) sconvb[tid] = conv_b[tid];
    {   // 256 kernel points: (sinT sinP, sinT cosP, cosT), flat index j*4+s
        float th = theta[tid], ph = phi[tid];
        float st = sinf(th), ct = cosf(th), sp = sinf(ph), cp = cosf(ph);
        ktx[tid] = st * sp; kty[tid] = st * cp; ktz[tid] = ct;
    }
    __syncthreads();

    const int lane = tid & 63, wave = tid >> 6;
    for (long base = (long)blockIdx.x * 4; base < NPAD; base += (long)gridDim.x * 4) {
        const long p = base + wave;
        const bool valid = (p < NPTS);
        float spat = 0.f, frcv = 0.f, kcv = 0.f, nrmv = 0.f;
        if (valid) {
            float cx = centre[p * 3], cy = centre[p * 3 + 1], cz = centre[p * 3 + 2];
            float h1 = sbsp2[lane] + cx * sWsp2t[0][lane] + cy * sWsp2t[1][lane] + cz * sWsp2t[2][lane];
            h1buf[wave][lane] = fmaxf(h1, 0.f);
            if (lane < 32) {
                float c0 = corner[p*9+0], c1 = corner[p*9+1], c2 = corner[p*9+2];
                float c3 = corner[p*9+3], c4 = corner[p*9+4], c5 = corner[p*9+5];
                float c6 = corner[p*9+6], c7 = corner[p*9+7], c8 = corner[p*9+8];
                float s0 = c0 + c3 + c6, s1 = c1 + c4 + c7, s2 = c2 + c5 + c8;
                mbuf[wave][lane] = sconvb[lane] + (1.f / 3.f) *
                    ((sconvt[0][lane] + sconvt[3][lane]) * s0 +
                     (sconvt[1][lane] + sconvt[4][lane]) * s1 +
                     (sconvt[2][lane] + sconvt[5][lane]) * s2);
            }
        }
        __syncthreads();
        if (valid) {
            float a = sbsp1[lane], h3 = sbfr3[lane];
#pragma unroll 8
            for (int k = 0; k < 64; ++k) a += h1buf[wave][k] * sWsp1t[k][lane];
#pragma unroll 8
            for (int k = 0; k < 32; ++k) h3 += mbuf[wave][k] * sWfr3t[k][lane];
            spat = a;
            h3buf[wave][lane] = fmaxf(h3, 0.f);
        }
        __syncthreads();
        if (valid) {
            float f4 = sbfr4[lane];
#pragma unroll 8
            for (int k = 0; k < 64; ++k) f4 += h3buf[wave][k] * sWfr4t[k][lane];
            frcv = f4;
            int nb0 = clampi(neighbour[p * 3]), nb1 = clampi(neighbour[p * 3 + 1]), nb2 = clampi(neighbour[p * 3 + 2]);
            float nx[4], ny[4], nz[4];
            nx[0] = normal[p * 3];          ny[0] = normal[p * 3 + 1];          nz[0] = normal[p * 3 + 2];
            nx[1] = normal[(long)nb0 * 3];  ny[1] = normal[(long)nb0 * 3 + 1];  nz[1] = normal[(long)nb0 * 3 + 2];
            nx[2] = normal[(long)nb1 * 3];  ny[2] = normal[(long)nb1 * 3 + 1];  nz[2] = normal[(long)nb1 * 3 + 2];
            nx[3] = normal[(long)nb2 * 3];  ny[3] = normal[(long)nb2 * 3 + 1];  nz[3] = normal[(long)nb2 * 3 + 2];
            float kcs = 0.f;
#pragma unroll
            for (int t = 0; t < 4; ++t)
#pragma unroll
                for (int s = 0; s < 4; ++s) {
                    float dx = nx[t] - ktx[lane * 4 + s];
                    float dy = ny[t] - kty[lane * 4 + s];
                    float dz = nz[t] - ktz[lane * 4 + s];
                    kcs += __expf(-12.5f * (dx * dx + dy * dy + dz * dz));  // 1/(2*0.2^2)=12.5
                }
            kcv = kcs * (1.f / 16.f);
            nrmv = (lane == 0) ? nx[0] : (lane == 1) ? ny[0] : (lane == 2) ? nz[0] : 0.f;
        }
        {
            __hip_bfloat16* row = cat1 + p * 256;
            row[lane] = f2bf(spat); row[64 + lane] = f2bf(frcv);
            row[128 + lane] = f2bf(kcv); row[192 + lane] = f2bf(nrmv);
        }
        __syncthreads();
    }
}

// ---------------------------------------------------------------------------
// agg1 = 0.25*(structural + 3 neighbors); structural = cat1 cols [64,195)
// ---------------------------------------------------------------------------
__global__ __launch_bounds__(256) void gather_agg1(
    const __hip_bfloat16* __restrict__ cat1, const int* __restrict__ neighbour,
    __hip_bfloat16* __restrict__ agg1)
{
    long p = (long)blockIdx.x * 4 + (threadIdx.x >> 6);
    int lane = threadIdx.x & 63;
    if (p >= NPAD) return;
    __hip_bfloat16* o = agg1 + p * 256;
    if (p >= NPTS) {
        __hip_bfloat16 z = f2bf(0.f);
        o[lane] = z; o[64 + lane] = z; o[128 + lane] = z; o[192 + lane] = z;
        return;
    }
    int nb0 = clampi(neighbour[p * 3]), nb1 = clampi(neighbour[p * 3 + 1]), nb2 = clampi(neighbour[p * 3 + 2]);
    const __hip_bfloat16* r0 = cat1 + p * 256 + 64;
    const __hip_bfloat16* r1 = cat1 + (long)nb0 * 256 + 64;
    const __hip_bfloat16* r2 = cat1 + (long)nb1 * 256 + 64;
    const __hip_bfloat16* r3 = cat1 + (long)nb2 * 256 + 64;
    float a = (bf2f(r0[lane]) + bf2f(r1[lane]) + bf2f(r2[lane]) + bf2f(r3[lane])) * 0.25f;
    float b = (bf2f(r0[64 + lane]) + bf2f(r1[64 + lane]) + bf2f(r2[64 + lane]) + bf2f(r3[64 + lane])) * 0.25f;
    float c = (lane < 3) ? (bf2f(r0[128 + lane]) + bf2f(r1[128 + lane]) + bf2f(r2[128 + lane]) + bf2f(r3[128 + lane])) * 0.25f : 0.f;
    o[lane] = f2bf(a); o[64 + lane] = f2bf(b); o[128 + lane] = f2bf(c); o[192 + lane] = f2bf(0.f);
}

// agg2 = 0.25*(out2 + 3 neighbors); out2 is NPAD x 256 (ld 256)
__global__ __launch_bounds__(256) void gather_agg2(
    const __hip_bfloat16* __restrict__ out2, const int* __restrict__ neighbour,
    __hip_bfloat16* __restrict__ agg2)
{
    long p = (long)blockIdx.x * 4 + (threadIdx.x >> 6);
    int lane = threadIdx.x & 63;
    if (p >= NPAD) return;
    __hip_bfloat16* o = agg2 + p * 256;
    if (p >= NPTS) {
        __hip_bfloat16 z = f2bf(0.f);
        o[lane] = z; o[64 + lane] = z; o[128 + lane] = z; o[192 + lane] = z;
        return;
    }
    int nb0 = clampi(neighbour[p * 3]), nb1 = clampi(neighbour[p * 3 + 1]), nb2 = clampi(neighbour[p * 3 + 2]);
    const __hip_bfloat16* r0 = out2 + p * 256;
    const __hip_bfloat16* r1 = out2 + (long)nb0 * 256;
    const __hip_bfloat16* r2 = out2 + (long)nb1 * 256;
    const __hip_bfloat16* r3 = out2 + (long)nb2 * 256;
#pragma unroll
    for (int q = 0; q < 4; ++q) {
        int c = q * 64 + lane;
        o[c] = f2bf((bf2f(r0[c]) + bf2f(r1[c]) + bf2f(r2[c]) + bf2f(r3[c])) * 0.25f);
    }
}

// ---------------------------------------------------------------------------
// m97-style 128x128 bf16 MFMA GEMM core, NT: C[m][n] = sum_k A[m][k]*B[n][k]
// A from up to 3 row-major sources split along K (32-multiples).
// ---------------------------------------------------------------------------
__device__ __forceinline__ void gemm_core(
    const __hip_bfloat16* A0, int lda0, int k0end,
    const __hip_bfloat16* A1, int lda1, int k1end,
    const __hip_bfloat16* A2, int lda2,
    const __hip_bfloat16* B, int K,
    u16* Asm, u16* Bsm, long rowbase, int colbase, int tid,
    f32x4 acc[4][4])
{
    const int lane = tid & 63, wave = tid >> 6;
    const int wr = wave >> 1, wc = wave & 1;
    const int m16 = lane & 15, kg = lane >> 4;
    for (int kt = 0; kt < K; kt += 32) {
        const __hip_bfloat16* Ap; long lda; int kl;
        if (kt < k0end)      { Ap = A0; lda = lda0; kl = kt; }
        else if (kt < k1end) { Ap = A1; lda = lda1; kl = kt - k0end; }
        else                 { Ap = A2; lda = lda2; kl = kt - k1end; }
#pragma unroll
        for (int i = 0; i < 2; ++i) {   // A tile: 128 rows x 32 cols
            int cid = i * 256 + tid;
            int row = cid >> 2, kc = cid & 3;
            gload_lds16(Ap + (rowbase + row) * lda + kl + kc * 8, Asm + cid * 8);
        }
#pragma unroll
        for (int i = 0; i < 2; ++i) {   // B tile: 128 weight rows x 32 cols
            int cid = i * 256 + tid;
            int row = cid >> 2, kc = cid & 3;
            gload_lds16(B + (long)(colbase + row) * K + kt + kc * 8, Bsm + cid * 8);
        }
        __syncthreads();
        bf16x8 af[4], bv[4];
#pragma unroll
        for (int i = 0; i < 4; ++i)
            af[i] = *(const bf16x8*)(Asm + ((wr * 64 + i * 16 + m16) * 32 + kg * 8));
#pragma unroll
        for (int j = 0; j < 4; ++j)
            bv[j] = *(const bf16x8*)(Bsm + ((wc * 64 + j * 16 + m16) * 32 + kg * 8));
#pragma unroll
        for (int i = 0; i < 4; ++i)
#pragma unroll
            for (int j = 0; j < 4; ++j)
                acc[i][j] = __builtin_amdgcn_mfma_f32_16x16x32_bf16(af[i], bv[j], acc[i][j], 0, 0, 0);
        __syncthreads();
    }
}

__global__ __launch_bounds__(256) void gemm_nt(
    const __hip_bfloat16* __restrict__ A0, int lda0, int k0end,
    const __hip_bfloat16* __restrict__ A1, int lda1, int k1end,
    const __hip_bfloat16* __restrict__ A2, int lda2,
    const __hip_bfloat16* __restrict__ B, int K,
    const float* __restrict__ bias,
    __hip_bfloat16* __restrict__ C, int ldc, int coloff)
{
    __shared__ __align__(16) u16 Asm[128 * 32];
    __shared__ __align__(16) u16 Bsm[128 * 32];
    const int tid = threadIdx.x;
    const long rowbase = (long)blockIdx.y * 128;
    const int colbase = blockIdx.x * 128;
    f32x4 acc[4][4] = {};
    gemm_core(A0, lda0, k0end, A1, lda1, k1end, A2, lda2, B, K, Asm, Bsm, rowbase, colbase, tid, acc);
    const int lane = tid & 63, wave = tid >> 6;
    const int wr = wave >> 1, wc = wave & 1;
    const int m16 = lane & 15, q = lane >> 4;
#pragma unroll
    for (int j = 0; j < 4; ++j) {
        int col = colbase + wc * 64 + j * 16 + m16;
        float bvv = bias[col];
#pragma unroll
        for (int i = 0; i < 4; ++i)
#pragma unroll
            for (int r = 0; r < 4; ++r) {
                long rowg = rowbase + wr * 64 + i * 16 + q * 4 + r;
                C[rowg * ldc + coloff + col] = f2bf(acc[i][j][r] + bvv);
            }
    }
}

// max-GEMM: g_enc[col] = atomicMax over valid rows (no bias; consts folded later)
__global__ __launch_bounds__(256) void gemm_nt_max(
    const __hip_bfloat16* __restrict__ A0, int lda0, int k0end,
    const __hip_bfloat16* __restrict__ A1, int lda1, int k1end,
    const __hip_bfloat16* __restrict__ A2, int lda2,
    const __hip_bfloat16* __restrict__ B, int K,
    unsigned* __restrict__ g_enc)
{
    __shared__ __align__(16) u16 Asm[128 * 32];
    __shared__ __align__(16) u16 Bsm[128 * 32];
    __shared__ float red[2][128];
    const int tid = threadIdx.x;
    const long rowbase = (long)blockIdx.y * 128;
    const int colbase = blockIdx.x * 128;
    f32x4 acc[4][4] = {};
    gemm_core(A0, lda0, k0end, A1, lda1, k1end, A2, lda2, B, K, Asm, Bsm, rowbase, colbase, tid, acc);
    const int lane = tid & 63, wave = tid >> 6;
    const int wr = wave >> 1, wc = wave & 1;
    const int m16 = lane & 15, q = lane >> 4;
#pragma unroll
    for (int j = 0; j < 4; ++j) {
        float m = -INFINITY;
#pragma unroll
        for (int i = 0; i < 4; ++i)
#pragma unroll
            for (int r = 0; r < 4; ++r) {
                long rowg = rowbase + wr * 64 + i * 16 + q * 4 + r;
                m = (rowg < NPTS) ? fmaxf(m, acc[i][j][r]) : m;   // mask pad rows
            }
        m = fmaxf(m, __shfl_xor(m, 16));
        m = fmaxf(m, __shfl_xor(m, 32));
        if (lane < 16) red[wr][wc * 64 + j * 16 + m16] = m;
    }
    __syncthreads();
    if (tid < 128) {
        float v = fmaxf(red[0][tid], red[1][tid]);
        atomicMax(g_enc + colbase + tid, enc_f32(v));
    }
}

// ---------------------------------------------------------------------------
// head: g = dec(g_enc)+cvec+b_m2 -> relu(W31) -> relu(W32) -> W33 -> logits
// ---------------------------------------------------------------------------
__global__ __launch_bounds__(256) void head_mlp(
    const unsigned* __restrict__ g_enc, const float* __restrict__ cvec,
    const float* __restrict__ b_m2,
    const float* __restrict__ W31, const float* __restrict__ b31,
    const float* __restrict__ W32, const float* __restrict__ b32,
    const float* __restrict__ W33, const float* __restrict__ b33,
    float* __restrict__ out)
{
    __shared__ float g[1024], h1[512], h2[256];
    const int tid = threadIdx.x, lane = tid & 63, wave = tid >> 6;
    for (int i = tid; i < 1024; i += 256) g[i] = dec_f32(g_enc[i]) + cvec[i] + b_m2[i];
    __syncthreads();
    for (int o = wave; o < 512; o += 4) {
        float a = 0.f;
        for (int k = lane; k < 1024; k += 64) a += g[k] * W31[o * 1024 + k];
#pragma unroll
        for (int off = 32; off > 0; off >>= 1) a += __shfl_xor(a, off);
        if (lane == 0) h1[o] = fmaxf(a + b31[o], 0.f);
    }
    __syncthreads();
    for (int o = wave; o < 256; o += 4) {
        float a = 0.f;
        for (int k = lane; k < 512; k += 64) a += h1[k] * W32[o * 512 + k];
#pragma unroll
        for (int off = 32; off > 0; off >>= 1) a += __shfl_xor(a, off);
        if (lane == 0) h2[o] = fmaxf(a + b32[o], 0.f);
    }
    __syncthreads();
    for (int o = wave; o < 40; o += 4) {
        float a = 0.f;
        for (int k = lane; k < 256; k += 64) a += h2[k] * W33[o * 256 + k];
#pragma unroll
        for (int off = 32; off > 0; off >>= 1) a += __shfl_xor(a, off);
        if (lane == 0) out[o] = a + b33[o];
    }
}

// ---------------------------------------------------------------------------
extern "C" void kernel_launch(void* const* d_in, const int* in_sizes, int n_in,
                              void* d_out, int out_size, void* d_ws, size_t ws_size,
                              hipStream_t stream)
{
    (void)in_sizes; (void)n_in; (void)out_size; (void)ws_size;
    const float* centre = (const float*)d_in[0];
    const float* corner = (const float*)d_in[1];
    const float* normal = (const float*)d_in[2];
    const int*   neighbour = (const int*)d_in[3];
    const float* W_sp2 = (const float*)d_in[4];
    const float* b_sp2 = (const float*)d_in[5];
    const float* W_sp1 = (const float*)d_in[6];
    const float* b_sp1 = (const float*)d_in[7];
    const float* conv_w = (const float*)d_in[8];
    const float* conv_b = (const float*)d_in[9];
    const float* W_fr3 = (const float*)d_in[10];
    const float* b_fr3 = (const float*)d_in[11];
    const float* W_fr4 = (const float*)d_in[12];
    const float* b_fr4 = (const float*)d_in[13];
    const float* theta = (const float*)d_in[14];
    const float* phi   = (const float*)d_in[15];
    const float* W_c1 = (const float*)d_in[16];
    const float* b_c1 = (const float*)d_in[17];
    const float* W_a1 = (const float*)d_in[18];
    const float* b_a1 = (const float*)d_in[19];
    const float* W_c2 = (const float*)d_in[20];
    const float* b_c2 = (const float*)d_in[21];
    const float* W_a2 = (const float*)d_in[22];
    const float* b_a2 = (const float*)d_in[23];
    const float* W_f  = (const float*)d_in[24];
    const float* b_f  = (const float*)d_in[25];
    const float* W_m2 = (const float*)d_in[26];
    const float* b_m2 = (const float*)d_in[27];
    const float* W_m31 = (const float*)d_in[28];
    const float* b_m31 = (const float*)d_in[29];
    const float* W_m32 = (const float*)d_in[30];
    const float* b_m32 = (const float*)d_in[31];
    const float* W_m33 = (const float*)d_in[32];
    const float* b_m33 = (const float*)d_in[33];

    char* ws = (char*)d_ws;
    size_t off = 0;
    auto alloc = [&](size_t bytes) { void* p = ws + off; off += (bytes + 255) & ~(size_t)255; return p; };
    // activations: 4 x NPADx256 bf16 = 102.5 MB
    __hip_bfloat16* cat1  = (__hip_bfloat16*)alloc((size_t)NPAD * 256 * 2);
    __hip_bfloat16* agg1  = (__hip_bfloat16*)alloc((size_t)NPAD * 256 * 2);
    __hip_bfloat16* out2  = (__hip_bfloat16*)alloc((size_t)NPAD * 256 * 2);
    __hip_bfloat16* agg2  = (__hip_bfloat16*)alloc((size_t)NPAD * 256 * 2);
    // weights / combined weights (~9 MB)
    float* Wc1p  = (float*)alloc((size_t)65536 * 4);
    float* Wa1pf = (float*)alloc((size_t)65536 * 4);
    __hip_bfloat16* Wa1pb = (__hip_bfloat16*)alloc((size_t)65536 * 2);
    __hip_bfloat16* Xw    = (__hip_bfloat16*)alloc((size_t)1024 * 768 * 2);  // [X1|X2|V]
    float* T3f  = (float*)alloc((size_t)1024 * 512 * 4);
    float* T4f  = (float*)alloc((size_t)1024 * 512 * 4);
    float* U1f  = (float*)alloc((size_t)1024 * 256 * 4);
    float* U2f  = (float*)alloc((size_t)1024 * 256 * 4);
    float* cvec = (float*)alloc(1024 * 4);
    unsigned* g_enc = (unsigned*)alloc(1024 * 4);

    prep<<<516, 256, 0, stream>>>(W_c1, W_a1, Wc1p, Wa1pf, Wa1pb, g_enc);

    // ---- collapse the affine chain into [X1|X2|V] (1024x768) + cvec ----
    // T3 = M2 + M3@Wfa ; T4 = M3@Wfb   (M1|M2|M3 = W_m2 col-splits 256/512/1024)
    wgemm<<<dim3(16, 32), 256, 0, stream>>>(W_m2 + 768, 1792, W_f, 1024,
        W_m2 + 256, 1792, T3f, (__hip_bfloat16*)nullptr, 512, 1024);
    wgemm<<<dim3(16, 32), 256, 0, stream>>>(W_m2 + 768, 1792, W_f + 512, 1024,
        (const float*)nullptr, 0, T4f, (__hip_bfloat16*)nullptr, 512, 1024);
    // U1 = M1 + T3@Wc2a ; U2 = T3@Wc2b
    wgemm<<<dim3(8, 32), 256, 0, stream>>>(T3f, 512, W_c2, 512,
        W_m2, 1792, U1f, (__hip_bfloat16*)nullptr, 256, 512);
    wgemm<<<dim3(8, 32), 256, 0, stream>>>(T3f, 512, W_c2 + 256, 512,
        (const float*)nullptr, 0, U2f, (__hip_bfloat16*)nullptr, 256, 512);
    // X1 = U1@Wc1p ; X2 = U2@Wa1pf ; V = T4@W_a2   -> Xw (bf16, ld 768)
    wgemm<<<dim3(8, 32), 256, 0, stream>>>(U1f, 256, Wc1p, 256,
        (const float*)nullptr, 0, (float*)nullptr, Xw, 768, 256);
    wgemm<<<dim3(8, 32), 256, 0, stream>>>(U2f, 256, Wa1pf, 256,
        (const float*)nullptr, 0, (float*)nullptr, Xw + 256, 768, 256);
    wgemm<<<dim3(8, 32), 256, 0, stream>>>(T4f, 512, W_a2, 256,
        (const float*)nullptr, 0, (float*)nullptr, Xw + 512, 768, 512);
    cvec_kernel<<<4, 256, 0, stream>>>(W_m2, T3f, T4f, U1f, U2f,
        b_f, b_c2, b_a2, b_c1, b_a1, cvec);

    // ---- per-point path ----
    featurize<<<2048, 256, 0, stream>>>(centre, corner, normal, neighbour,
        W_sp2, b_sp2, W_sp1, b_sp1, conv_w, conv_b, W_fr3, b_fr3, W_fr4, b_fr4, theta, phi, cat1);
    gather_agg1<<<NPAD / 4, 256, 0, stream>>>(cat1, neighbour, agg1);
    // out2 = agg1 @ Wa1p^T + b_a1  (needed only for the agg2 gather)
    gemm_nt<<<dim3(2, NPAD / 128), 256, 0, stream>>>(agg1, 256, 256, agg1, 256, 256, agg1, 256,
                                                     Wa1pb, 256, b_a1, out2, 256, 0);
    gather_agg2<<<NPAD / 4, 256, 0, stream>>>(out2, neighbour, agg2);
    // g = max_n([cat1|agg1|agg2] @ Xw^T)  (78.7 GF, the whole fused chain)
    gemm_nt_max<<<dim3(8, NPAD / 128), 256, 0, stream>>>(cat1, 256, 256, agg1, 256, 512, agg2, 256,
                                                         Xw, 768, g_enc);
    head_mlp<<<1, 256, 0, stream>>>(g_enc, cvec, b_m2, W_m31, b_m31, W_m32, b_m32, W_m33, b_m33,
                                    (float*)d_out);
}

// Round 4
// 758.200 us; speedup vs baseline: 2.0047x; 2.0047x over previous
//
#include <hip/hip_runtime.h>
#include <hip/hip_bf16.h>
#include <stdint.h>

#define NPTS 50000
#define NPAD 50048   // 391 * 128 row tiles

typedef unsigned short u16;
typedef __attribute__((ext_vector_type(8))) __bf16 bf16x8;
typedef __attribute__((ext_vector_type(4))) float f32x4;

__device__ __forceinline__ float bf2f(__hip_bfloat16 v) { return __bfloat162float(v); }
__device__ __forceinline__ __hip_bfloat16 f2bf(float v) { return __float2bfloat16(v); }
__device__ __forceinline__ int clampi(int v) { return v < 0 ? 0 : (v >= NPTS ? NPTS - 1 : v); }

// monotone float <-> uint encode for atomicMax over signed floats
__device__ __forceinline__ unsigned enc_f32(float f) {
    unsigned b = __float_as_uint(f);
    return (b & 0x80000000u) ? ~b : (b | 0x80000000u);
}
__device__ __forceinline__ float dec_f32(unsigned u) {
    return (u & 0x80000000u) ? __uint_as_float(u & 0x7fffffffu) : __uint_as_float(~u);
}

// async global->LDS, 16B per lane; LDS dest must be wave-uniform base + lane*16
__device__ __forceinline__ void gload_lds16(const void* g, void* l) {
    __builtin_amdgcn_global_load_lds((__attribute__((address_space(1))) void*)g,
                                     (__attribute__((address_space(3))) void*)l, 16, 0, 0);
}

// ---------------------------------------------------------------------------
// prep: zero-pad W_c1 (256x195)->fp32, W_a1 (256x131)->fp32+bf16; g_enc=-inf
// ---------------------------------------------------------------------------
__global__ __launch_bounds__(256) void prep(
    const float* __restrict__ W_c1, const float* __restrict__ W_a1,
    float* __restrict__ Wc1p, float* __restrict__ Wa1pf, __hip_bfloat16* __restrict__ Wa1pb,
    unsigned* __restrict__ g_enc)
{
    int i = blockIdx.x * 256 + threadIdx.x;
    if (i < 65536) {
        int o = i >> 8, k = i & 255;
        Wc1p[i] = (k < 195) ? W_c1[o * 195 + k] : 0.f;
    } else if (i < 131072) {
        int t = i - 65536;
        int o = t >> 8, k = t & 255;
        float v = (k < 131) ? W_a1[o * 131 + k] : 0.f;
        Wa1pf[t] = v;
        Wa1pb[t] = f2bf(v);
    } else if (i < 132096) {
        g_enc[i - 131072] = 0x007FFFFFu;   // enc(-inf)
    }
}

// ---------------------------------------------------------------------------
// wgemm (fp32): C[i][j] = sum_k A[i*lda+k]*B[k*ldb+j] (+ D[i*ldd+j]).
// M,N,K multiples of 32. 32x32 tiles. Writes fp32 (Cf) and/or bf16 (Cb).
// ---------------------------------------------------------------------------
__global__ __launch_bounds__(256) void wgemm(
    const float* __restrict__ A, int lda,
    const float* __restrict__ B, int ldb,
    const float* __restrict__ D, int ldd,
    float* __restrict__ Cf, __hip_bfloat16* __restrict__ Cb, int ldc,
    int K)
{
    __shared__ float sA[32][33], sB[32][33];
    const int bj = blockIdx.x, bi = blockIdx.y;
    const int t = threadIdx.x, tx = t & 31, ty = t >> 5;   // ty in [0,8)
    float acc[4] = {0.f, 0.f, 0.f, 0.f};
    for (int k0 = 0; k0 < K; k0 += 32) {
#pragma unroll
        for (int q = 0; q < 4; ++q) {
            int idx = q * 256 + t, r = idx >> 5, c = idx & 31;
            sA[r][c] = A[(long)(bi * 32 + r) * lda + k0 + c];
            sB[r][c] = B[(long)(k0 + r) * ldb + bj * 32 + c];
        }
        __syncthreads();
#pragma unroll 8
        for (int c = 0; c < 32; ++c) {
            float bv = sB[c][tx];
#pragma unroll
            for (int q = 0; q < 4; ++q) acc[q] += sA[ty + q * 8][c] * bv;
        }
        __syncthreads();
    }
#pragma unroll
    for (int q = 0; q < 4; ++q) {
        int r = bi * 32 + ty + q * 8, cidx = bj * 32 + tx;
        float v = acc[q];
        if (D)  v += D[(long)r * ldd + cidx];
        if (Cf) Cf[(long)r * ldc + cidx] = v;
        if (Cb) Cb[(long)r * ldc + cidx] = f2bf(v);
    }
}

// cvec[i] = b_f@M3^T + b_c2@T3^T + b_a2@T4^T + b_c1@U1^T + b_a1@U2^T
__global__ __launch_bounds__(256) void cvec_kernel(
    const float* __restrict__ W_m2,
    const float* __restrict__ T3f, const float* __restrict__ T4f,
    const float* __restrict__ U1f, const float* __restrict__ U2f,
    const float* __restrict__ b_f, const float* __restrict__ b_c2,
    const float* __restrict__ b_a2, const float* __restrict__ b_c1,
    const float* __restrict__ b_a1,
    float* __restrict__ cvec)
{
    int i = blockIdx.x * 256 + threadIdx.x;
    if (i >= 1024) return;
    float s = 0.f;
    for (int k = 0; k < 1024; ++k) s += b_f[k] * W_m2[(long)i * 1792 + 768 + k];
    for (int k = 0; k < 512;  ++k) s += b_c2[k] * T3f[i * 512 + k];
    for (int k = 0; k < 512;  ++k) s += b_a2[k] * T4f[i * 512 + k];
    for (int k = 0; k < 256;  ++k) s += b_c1[k] * U1f[i * 256 + k];
    for (int k = 0; k < 256;  ++k) s += b_a1[k] * U2f[i * 256 + k];
    cvec[i] = s;
}

// ---------------------------------------------------------------------------
// featurize: one wave per point. cat1 row (ld 256):
//   [0:64) spatial | [64:128) frc | [128:192) kc | [192:195) normal | zeros
// rows [NPTS,NPAD) zero-filled.
// ---------------------------------------------------------------------------
__global__ __launch_bounds__(256) void featurize(
    const float* __restrict__ centre, const float* __restrict__ corner,
    const float* __restrict__ normal, const int* __restrict__ neighbour,
    const float* __restrict__ W_sp2, const float* __restrict__ b_sp2,
    const float* __restrict__ W_sp1, const float* __restrict__ b_sp1,
    const float* __restrict__ conv_w, const float* __restrict__ conv_b,
    const float* __restrict__ W_fr3, const float* __restrict__ b_fr3,
    const float* __restrict__ W_fr4, const float* __restrict__ b_fr4,
    const float* __restrict__ theta, const float* __restrict__ phi,
    __hip_bfloat16* __restrict__ cat1)
{
    __shared__ float sWsp2t[3][64];  __shared__ float sbsp2[64];
    __shared__ float sWsp1t[64][64]; __shared__ float sbsp1[64];   // [k][j] transposed
    __shared__ float sconvt[6][32];  __shared__ float sconvb[32];
    __shared__ float sWfr3t[32][64]; __shared__ float sbfr3[64];
    __shared__ float sWfr4t[64][64]; __shared__ float sbfr4[64];
    __shared__ float ktx[256], kty[256], ktz[256];
    __shared__ float h1buf[4][64], mbuf[4][32], h3buf[4][64];

    const int tid = threadIdx.x;
    for (int i = tid; i < 4096; i += 256) { int j = i >> 6, k = i & 63; sWsp1t[k][j] = W_sp1[i]; }
    for (int i = tid; i < 4096; i += 256) { int j = i >> 6, k = i & 63; sWfr4t[k][j] = W_fr4[i]; }
    for (int i = tid; i < 2048; i += 256) { int j = i >> 5, k = i & 31; sWfr3t[k][j] = W_fr3[i]; }
    for (int i = tid; i < 192; i += 256) { int j = i / 3, k = i % 3; sWsp2t[k][j] = W_sp2[i]; }
    for (int i = tid; i < 192; i += 256) { int o = i / 6, k = i % 6; sconvt[k][o] = conv_w[i]; }
    if (tid < 64) {
        sbsp2[tid] = b_sp2[tid]; sbsp1[tid] = b_sp1[tid];
        sbfr3[tid] = b_fr3[tid]; sbfr4[tid] = b_fr4[tid];
    }
    if (tid < 32) sconvb[tid] = conv_b[tid];
    {   // 256 kernel points: (sinT sinP, sinT cosP, cosT), flat index j*4+s
        float th = theta[tid], ph = phi[tid];
        float st = sinf(th), ct = cosf(th), sp = sinf(ph), cp = cosf(ph);
        ktx[tid] = st * sp; kty[tid] = st * cp; ktz[tid] = ct;
    }
    __syncthreads();

    const int lane = tid & 63, wave = tid >> 6;
    for (long base = (long)blockIdx.x * 4; base < NPAD; base += (long)gridDim.x * 4) {
        const long p = base + wave;
        const bool valid = (p < NPTS);
        float spat = 0.f, frcv = 0.f, kcv = 0.f, nrmv = 0.f;
        if (valid) {
            float cx = centre[p * 3], cy = centre[p * 3 + 1], cz = centre[p * 3 + 2];
            float h1 = sbsp2[lane] + cx * sWsp2t[0][lane] + cy * sWsp2t[1][lane] + cz * sWsp2t[2][lane];
            h1buf[wave][lane] = fmaxf(h1, 0.f);
            if (lane < 32) {
                float c0 = corner[p*9+0], c1 = corner[p*9+1], c2 = corner[p*9+2];
                float c3 = corner[p*9+3], c4 = corner[p*9+4], c5 = corner[p*9+5];
                float c6 = corner[p*9+6], c7 = corner[p*9+7], c8 = corner[p*9+8];
                float s0 = c0 + c3 + c6, s1 = c1 + c4 + c7, s2 = c2 + c5 + c8;
                mbuf[wave][lane] = sconvb[lane] + (1.f / 3.f) *
                    ((sconvt[0][lane] + sconvt[3][lane]) * s0 +
                     (sconvt[1][lane] + sconvt[4][lane]) * s1 +
                     (sconvt[2][lane] + sconvt[5][lane]) * s2);
            }
        }
        __syncthreads();
        if (valid) {
            float a = sbsp1[lane], h3 = sbfr3[lane];
#pragma unroll 8
            for (int k = 0; k < 64; ++k) a += h1buf[wave][k] * sWsp1t[k][lane];
#pragma unroll 8
            for (int k = 0; k < 32; ++k) h3 += mbuf[wave][k] * sWfr3t[k][lane];
            spat = a;
            h3buf[wave][lane] = fmaxf(h3, 0.f);
        }
        __syncthreads();
        if (valid) {
            float f4 = sbfr4[lane];
#pragma unroll 8
            for (int k = 0; k < 64; ++k) f4 += h3buf[wave][k] * sWfr4t[k][lane];
            frcv = f4;
            int nb0 = clampi(neighbour[p * 3]), nb1 = clampi(neighbour[p * 3 + 1]), nb2 = clampi(neighbour[p * 3 + 2]);
            float nx[4], ny[4], nz[4];
            nx[0] = normal[p * 3];          ny[0] = normal[p * 3 + 1];          nz[0] = normal[p * 3 + 2];
            nx[1] = normal[(long)nb0 * 3];  ny[1] = normal[(long)nb0 * 3 + 1];  nz[1] = normal[(long)nb0 * 3 + 2];
            nx[2] = normal[(long)nb1 * 3];  ny[2] = normal[(long)nb1 * 3 + 1];  nz[2] = normal[(long)nb1 * 3 + 2];
            nx[3] = normal[(long)nb2 * 3];  ny[3] = normal[(long)nb2 * 3 + 1];  nz[3] = normal[(long)nb2 * 3 + 2];
            float kcs = 0.f;
#pragma unroll
            for (int t = 0; t < 4; ++t)
#pragma unroll
                for (int s = 0; s < 4; ++s) {
                    float dx = nx[t] - ktx[lane * 4 + s];
                    float dy = ny[t] - kty[lane * 4 + s];
                    float dz = nz[t] - ktz[lane * 4 + s];
                    kcs += __expf(-12.5f * (dx * dx + dy * dy + dz * dz));  // 1/(2*0.2^2)=12.5
                }
            kcv = kcs * (1.f / 16.f);
            nrmv = (lane == 0) ? nx[0] : (lane == 1) ? ny[0] : (lane == 2) ? nz[0] : 0.f;
        }
        {
            __hip_bfloat16* row = cat1 + p * 256;
            row[lane] = f2bf(spat); row[64 + lane] = f2bf(frcv);
            row[128 + lane] = f2bf(kcv); row[192 + lane] = f2bf(nrmv);
        }
        __syncthreads();
    }
}

// ---------------------------------------------------------------------------
// agg1 = 0.25*(structural + 3 neighbors); structural = cat1 cols [64,195)
// ---------------------------------------------------------------------------
__global__ __launch_bounds__(256) void gather_agg1(
    const __hip_bfloat16* __restrict__ cat1, const int* __restrict__ neighbour,
    __hip_bfloat16* __restrict__ agg1)
{
    long p = (long)blockIdx.x * 4 + (threadIdx.x >> 6);
    int lane = threadIdx.x & 63;
    if (p >= NPAD) return;
    __hip_bfloat16* o = agg1 + p * 256;
    if (p >= NPTS) {
        __hip_bfloat16 z = f2bf(0.f);
        o[lane] = z; o[64 + lane] = z; o[128 + lane] = z; o[192 + lane] = z;
        return;
    }
    int nb0 = clampi(neighbour[p * 3]), nb1 = clampi(neighbour[p * 3 + 1]), nb2 = clampi(neighbour[p * 3 + 2]);
    const __hip_bfloat16* r0 = cat1 + p * 256 + 64;
    const __hip_bfloat16* r1 = cat1 + (long)nb0 * 256 + 64;
    const __hip_bfloat16* r2 = cat1 + (long)nb1 * 256 + 64;
    const __hip_bfloat16* r3 = cat1 + (long)nb2 * 256 + 64;
    float a = (bf2f(r0[lane]) + bf2f(r1[lane]) + bf2f(r2[lane]) + bf2f(r3[lane])) * 0.25f;
    float b = (bf2f(r0[64 + lane]) + bf2f(r1[64 + lane]) + bf2f(r2[64 + lane]) + bf2f(r3[64 + lane])) * 0.25f;
    float c = (lane < 3) ? (bf2f(r0[128 + lane]) + bf2f(r1[128 + lane]) + bf2f(r2[128 + lane]) + bf2f(r3[128 + lane])) * 0.25f : 0.f;
    o[lane] = f2bf(a); o[64 + lane] = f2bf(b); o[128 + lane] = f2bf(c); o[192 + lane] = f2bf(0.f);
}

// agg2 = 0.25*(out2 + 3 neighbors); out2 is NPAD x 256 (ld 256)
__global__ __launch_bounds__(256) void gather_agg2(
    const __hip_bfloat16* __restrict__ out2, const int* __restrict__ neighbour,
    __hip_bfloat16* __restrict__ agg2)
{
    long p = (long)blockIdx.x * 4 + (threadIdx.x >> 6);
    int lane = threadIdx.x & 63;
    if (p >= NPAD) return;
    __hip_bfloat16* o = agg2 + p * 256;
    if (p >= NPTS) {
        __hip_bfloat16 z = f2bf(0.f);
        o[lane] = z; o[64 + lane] = z; o[128 + lane] = z; o[192 + lane] = z;
        return;
    }
    int nb0 = clampi(neighbour[p * 3]), nb1 = clampi(neighbour[p * 3 + 1]), nb2 = clampi(neighbour[p * 3 + 2]);
    const __hip_bfloat16* r0 = out2 + p * 256;
    const __hip_bfloat16* r1 = out2 + (long)nb0 * 256;
    const __hip_bfloat16* r2 = out2 + (long)nb1 * 256;
    const __hip_bfloat16* r3 = out2 + (long)nb2 * 256;
#pragma unroll
    for (int q = 0; q < 4; ++q) {
        int c = q * 64 + lane;
        o[c] = f2bf((bf2f(r0[c]) + bf2f(r1[c]) + bf2f(r2[c]) + bf2f(r3[c])) * 0.25f);
    }
}

// ---------------------------------------------------------------------------
// m97-style 128x128 bf16 MFMA GEMM core, NT: C[m][n] = sum_k A[m][k]*B[n][k]
// A from up to 3 row-major sources split along K (32-multiples).
// ---------------------------------------------------------------------------
__device__ __forceinline__ void gemm_core(
    const __hip_bfloat16* A0, int lda0, int k0end,
    const __hip_bfloat16* A1, int lda1, int k1end,
    const __hip_bfloat16* A2, int lda2,
    const __hip_bfloat16* B, int K,
    u16* Asm, u16* Bsm, long rowbase, int colbase, int tid,
    f32x4 acc[4][4])
{
    const int lane = tid & 63, wave = tid >> 6;
    const int wr = wave >> 1, wc = wave & 1;
    const int m16 = lane & 15, kg = lane >> 4;
    for (int kt = 0; kt < K; kt += 32) {
        const __hip_bfloat16* Ap; long lda; int kl;
        if (kt < k0end)      { Ap = A0; lda = lda0; kl = kt; }
        else if (kt < k1end) { Ap = A1; lda = lda1; kl = kt - k0end; }
        else                 { Ap = A2; lda = lda2; kl = kt - k1end; }
#pragma unroll
        for (int i = 0; i < 2; ++i) {   // A tile: 128 rows x 32 cols
            int cid = i * 256 + tid;
            int row = cid >> 2, kc = cid & 3;
            gload_lds16(Ap + (rowbase + row) * lda + kl + kc * 8, Asm + cid * 8);
        }
#pragma unroll
        for (int i = 0; i < 2; ++i) {   // B tile: 128 weight rows x 32 cols
            int cid = i * 256 + tid;
            int row = cid >> 2, kc = cid & 3;
            gload_lds16(B + (long)(colbase + row) * K + kt + kc * 8, Bsm + cid * 8);
        }
        __syncthreads();
        bf16x8 af[4], bv[4];
#pragma unroll
        for (int i = 0; i < 4; ++i)
            af[i] = *(const bf16x8*)(Asm + ((wr * 64 + i * 16 + m16) * 32 + kg * 8));
#pragma unroll
        for (int j = 0; j < 4; ++j)
            bv[j] = *(const bf16x8*)(Bsm + ((wc * 64 + j * 16 + m16) * 32 + kg * 8));
#pragma unroll
        for (int i = 0; i < 4; ++i)
#pragma unroll
            for (int j = 0; j < 4; ++j)
                acc[i][j] = __builtin_amdgcn_mfma_f32_16x16x32_bf16(af[i], bv[j], acc[i][j], 0, 0, 0);
        __syncthreads();
    }
}

__global__ __launch_bounds__(256) void gemm_nt(
    const __hip_bfloat16* __restrict__ A0, int lda0, int k0end,
    const __hip_bfloat16* __restrict__ A1, int lda1, int k1end,
    const __hip_bfloat16* __restrict__ A2, int lda2,
    const __hip_bfloat16* __restrict__ B, int K,
    const float* __restrict__ bias,
    __hip_bfloat16* __restrict__ C, int ldc, int coloff)
{
    __shared__ __align__(16) u16 Asm[128 * 32];
    __shared__ __align__(16) u16 Bsm[128 * 32];
    const int tid = threadIdx.x;
    const long rowbase = (long)blockIdx.y * 128;
    const int colbase = blockIdx.x * 128;
    f32x4 acc[4][4] = {};
    gemm_core(A0, lda0, k0end, A1, lda1, k1end, A2, lda2, B, K, Asm, Bsm, rowbase, colbase, tid, acc);
    const int lane = tid & 63, wave = tid >> 6;
    const int wr = wave >> 1, wc = wave & 1;
    const int m16 = lane & 15, q = lane >> 4;
#pragma unroll
    for (int j = 0; j < 4; ++j) {
        int col = colbase + wc * 64 + j * 16 + m16;
        float bvv = bias[col];
#pragma unroll
        for (int i = 0; i < 4; ++i)
#pragma unroll
            for (int r = 0; r < 4; ++r) {
                long rowg = rowbase + wr * 64 + i * 16 + q * 4 + r;
                C[rowg * ldc + coloff + col] = f2bf(acc[i][j][r] + bvv);
            }
    }
}

// max-GEMM: g_enc[col] = atomicMax over valid rows (no bias; consts folded later)
__global__ __launch_bounds__(256) void gemm_nt_max(
    const __hip_bfloat16* __restrict__ A0, int lda0, int k0end,
    const __hip_bfloat16* __restrict__ A1, int lda1, int k1end,
    const __hip_bfloat16* __restrict__ A2, int lda2,
    const __hip_bfloat16* __restrict__ B, int K,
    unsigned* __restrict__ g_enc)
{
    __shared__ __align__(16) u16 Asm[128 * 32];
    __shared__ __align__(16) u16 Bsm[128 * 32];
    __shared__ float red[2][128];
    const int tid = threadIdx.x;
    const long rowbase = (long)blockIdx.y * 128;
    const int colbase = blockIdx.x * 128;
    f32x4 acc[4][4] = {};
    gemm_core(A0, lda0, k0end, A1, lda1, k1end, A2, lda2, B, K, Asm, Bsm, rowbase, colbase, tid, acc);
    const int lane = tid & 63, wave = tid >> 6;
    const int wr = wave >> 1, wc = wave & 1;
    const int m16 = lane & 15, q = lane >> 4;
#pragma unroll
    for (int j = 0; j < 4; ++j) {
        float m = -INFINITY;
#pragma unroll
        for (int i = 0; i < 4; ++i)
#pragma unroll
            for (int r = 0; r < 4; ++r) {
                long rowg = rowbase + wr * 64 + i * 16 + q * 4 + r;
                m = (rowg < NPTS) ? fmaxf(m, acc[i][j][r]) : m;   // mask pad rows
            }
        m = fmaxf(m, __shfl_xor(m, 16));
        m = fmaxf(m, __shfl_xor(m, 32));
        if (lane < 16) red[wr][wc * 64 + j * 16 + m16] = m;
    }
    __syncthreads();
    if (tid < 128) {
        float v = fmaxf(red[0][tid], red[1][tid]);
        atomicMax(g_enc + colbase + tid, enc_f32(v));
    }
}

// ---------------------------------------------------------------------------
// parallel head: g = dec(g_enc)+cvec+b_m2, then 3 linear layers, one
// output column per wave (latency fix for the single-block head_mlp).
// ---------------------------------------------------------------------------
__global__ __launch_bounds__(256) void head_g(
    const unsigned* __restrict__ g_enc, const float* __restrict__ cvec,
    const float* __restrict__ b_m2, float* __restrict__ g)
{
    int i = blockIdx.x * 256 + threadIdx.x;
    if (i < 1024) g[i] = dec_f32(g_enc[i]) + cvec[i] + b_m2[i];
}

__global__ __launch_bounds__(256) void head_lin(
    const float* __restrict__ in, const float* __restrict__ W,
    const float* __restrict__ b, float* __restrict__ out,
    int In, int Out, int do_relu)
{
    int o = blockIdx.x * 4 + (threadIdx.x >> 6);   // one output per wave
    int lane = threadIdx.x & 63;
    if (o >= Out) return;
    float a = 0.f;
    for (int k = lane; k < In; k += 64) a += in[k] * W[(long)o * In + k];
#pragma unroll
    for (int off = 32; off > 0; off >>= 1) a += __shfl_xor(a, off);
    if (lane == 0) {
        float v = a + b[o];
        out[o] = do_relu ? fmaxf(v, 0.f) : v;
    }
}

// ---------------------------------------------------------------------------
extern "C" void kernel_launch(void* const* d_in, const int* in_sizes, int n_in,
                              void* d_out, int out_size, void* d_ws, size_t ws_size,
                              hipStream_t stream)
{
    (void)in_sizes; (void)n_in; (void)out_size; (void)ws_size;
    const float* centre = (const float*)d_in[0];
    const float* corner = (const float*)d_in[1];
    const float* normal = (const float*)d_in[2];
    const int*   neighbour = (const int*)d_in[3];
    const float* W_sp2 = (const float*)d_in[4];
    const float* b_sp2 = (const float*)d_in[5];
    const float* W_sp1 = (const float*)d_in[6];
    const float* b_sp1 = (const float*)d_in[7];
    const float* conv_w = (const float*)d_in[8];
    const float* conv_b = (const float*)d_in[9];
    const float* W_fr3 = (const float*)d_in[10];
    const float* b_fr3 = (const float*)d_in[11];
    const float* W_fr4 = (const float*)d_in[12];
    const float* b_fr4 = (const float*)d_in[13];
    const float* theta = (const float*)d_in[14];
    const float* phi   = (const float*)d_in[15];
    const float* W_c1 = (const float*)d_in[16];
    const float* b_c1 = (const float*)d_in[17];
    const float* W_a1 = (const float*)d_in[18];
    const float* b_a1 = (const float*)d_in[19];
    const float* W_c2 = (const float*)d_in[20];
    const float* b_c2 = (const float*)d_in[21];
    const float* W_a2 = (const float*)d_in[22];
    const float* b_a2 = (const float*)d_in[23];
    const float* W_f  = (const float*)d_in[24];
    const float* b_f  = (const float*)d_in[25];
    const float* W_m2 = (const float*)d_in[26];
    const float* b_m2 = (const float*)d_in[27];
    const float* W_m31 = (const float*)d_in[28];
    const float* b_m31 = (const float*)d_in[29];
    const float* W_m32 = (const float*)d_in[30];
    const float* b_m32 = (const float*)d_in[31];
    const float* W_m33 = (const float*)d_in[32];
    const float* b_m33 = (const float*)d_in[33];

    char* ws = (char*)d_ws;
    size_t off = 0;
    auto alloc = [&](size_t bytes) { void* p = ws + off; off += (bytes + 255) & ~(size_t)255; return p; };
    // activations: 4 x NPADx256 bf16 = 102.5 MB
    __hip_bfloat16* cat1  = (__hip_bfloat16*)alloc((size_t)NPAD * 256 * 2);
    __hip_bfloat16* agg1  = (__hip_bfloat16*)alloc((size_t)NPAD * 256 * 2);
    __hip_bfloat16* out2  = (__hip_bfloat16*)alloc((size_t)NPAD * 256 * 2);
    __hip_bfloat16* agg2  = (__hip_bfloat16*)alloc((size_t)NPAD * 256 * 2);
    // weights / combined weights (~9 MB)
    float* Wc1p  = (float*)alloc((size_t)65536 * 4);
    float* Wa1pf = (float*)alloc((size_t)65536 * 4);
    __hip_bfloat16* Wa1pb = (__hip_bfloat16*)alloc((size_t)65536 * 2);
    __hip_bfloat16* Xw    = (__hip_bfloat16*)alloc((size_t)1024 * 768 * 2);  // [X1|X2|V]
    float* T3f  = (float*)alloc((size_t)1024 * 512 * 4);
    float* T4f  = (float*)alloc((size_t)1024 * 512 * 4);
    float* U1f  = (float*)alloc((size_t)1024 * 256 * 4);
    float* U2f  = (float*)alloc((size_t)1024 * 256 * 4);
    float* cvec = (float*)alloc(1024 * 4);
    unsigned* g_enc = (unsigned*)alloc(1024 * 4);
    float* gvec = (float*)alloc(1024 * 4);
    float* h1   = (float*)alloc(512 * 4);
    float* h2   = (float*)alloc(256 * 4);

    prep<<<516, 256, 0, stream>>>(W_c1, W_a1, Wc1p, Wa1pf, Wa1pb, g_enc);

    // ---- collapse the affine chain into [X1|X2|V] (1024x768) + cvec ----
    // T3 = M2 + M3@Wfa ; T4 = M3@Wfb   (M1|M2|M3 = W_m2 col-splits 256/512/1024)
    wgemm<<<dim3(16, 32), 256, 0, stream>>>(W_m2 + 768, 1792, W_f, 1024,
        W_m2 + 256, 1792, T3f, (__hip_bfloat16*)nullptr, 512, 1024);
    wgemm<<<dim3(16, 32), 256, 0, stream>>>(W_m2 + 768, 1792, W_f + 512, 1024,
        (const float*)nullptr, 0, T4f, (__hip_bfloat16*)nullptr, 512, 1024);
    // U1 = M1 + T3@Wc2a ; U2 = T3@Wc2b
    wgemm<<<dim3(8, 32), 256, 0, stream>>>(T3f, 512, W_c2, 512,
        W_m2, 1792, U1f, (__hip_bfloat16*)nullptr, 256, 512);
    wgemm<<<dim3(8, 32), 256, 0, stream>>>(T3f, 512, W_c2 + 256, 512,
        (const float*)nullptr, 0, U2f, (__hip_bfloat16*)nullptr, 256, 512);
    // X1 = U1@Wc1p ; X2 = U2@Wa1pf ; V = T4@W_a2   -> Xw (bf16, ld 768)
    wgemm<<<dim3(8, 32), 256, 0, stream>>>(U1f, 256, Wc1p, 256,
        (const float*)nullptr, 0, (float*)nullptr, Xw, 768, 256);
    wgemm<<<dim3(8, 32), 256, 0, stream>>>(U2f, 256, Wa1pf, 256,
        (const float*)nullptr, 0, (float*)nullptr, Xw + 256, 768, 256);
    wgemm<<<dim3(8, 32), 256, 0, stream>>>(T4f, 512, W_a2, 256,
        (const float*)nullptr, 0, (float*)nullptr, Xw + 512, 768, 512);
    cvec_kernel<<<4, 256, 0, stream>>>(W_m2, T3f, T4f, U1f, U2f,
        b_f, b_c2, b_a2, b_c1, b_a1, cvec);

    // ---- per-point path ----
    featurize<<<2048, 256, 0, stream>>>(centre, corner, normal, neighbour,
        W_sp2, b_sp2, W_sp1, b_sp1, conv_w, conv_b, W_fr3, b_fr3, W_fr4, b_fr4, theta, phi, cat1);
    gather_agg1<<<NPAD / 4, 256, 0, stream>>>(cat1, neighbour, agg1);
    // out2 = agg1 @ Wa1p^T + b_a1  (needed only for the agg2 gather)
    gemm_nt<<<dim3(2, NPAD / 128), 256, 0, stream>>>(agg1, 256, 256, agg1, 256, 256, agg1, 256,
                                                     Wa1pb, 256, b_a1, out2, 256, 0);
    gather_agg2<<<NPAD / 4, 256, 0, stream>>>(out2, neighbour, agg2);
    // g = max_n([cat1|agg1|agg2] @ Xw^T)  (78.7 GF, the whole fused chain)
    gemm_nt_max<<<dim3(8, NPAD / 128), 256, 0, stream>>>(cat1, 256, 256, agg1, 256, 512, agg2, 256,
                                                         Xw, 768, g_enc);
    // ---- parallel head ----
    head_g<<<4, 256, 0, stream>>>(g_enc, cvec, b_m2, gvec);
    head_lin<<<128, 256, 0, stream>>>(gvec, W_m31, b_m31, h1, 1024, 512, 1);
    head_lin<<<64, 256, 0, stream>>>(h1, W_m32, b_m32, h2, 512, 256, 1);
    head_lin<<<10, 256, 0, stream>>>(h2, W_m33, b_m33, (float*)d_out, 256, 40, 0);
}